// Round 7
// baseline (131.814 us; speedup 1.0000x reference)
//
#include <hip/hip_runtime.h>
#include <cstdint>

#define THREADS 256
static constexpr int BS   = 4096;
static constexpr int C    = 16384;
static constexpr int D    = 128;
static constexpr int HALF = 2048;   // rows 0..2047 pair with rows 2048..4095
static constexpr int NPOS = 4;
static constexpr int NNEG = 20;
static constexpr int NSEL = 24;
static constexpr int QPT  = 16;     // int4 quads per thread (16*4 = 64 cols)

// Pre-filter: only comps with raw bits >= TH enter the per-thread top-2.
// Top 1/128 of u32 -> expected ~128 above-thresh negatives per row (need 20;
// P(shortfall) ~ e^-73). Selection stays EXACT regardless: the cooperative
// rebuild recomputes a thread's next candidate with no threshold.
static constexpr uint32_t TH = 0xFE000000u;

// 1-instruction rotate: v_alignbit_b32(x,x,32-r) == rotl(x,r)
__device__ __forceinline__ uint32_t rotl32(uint32_t x, int r) {
  return __builtin_amdgcn_alignbit(x, x, 32 - r);
}

// ---- JAX threefry2x32 (20 rounds), key = PRNGKey(42) = [0, 42] ----
__device__ __forceinline__ void tf2x32(uint32_t x0, uint32_t x1,
                                       uint32_t& o0, uint32_t& o1) {
  constexpr uint32_t ks0 = 0u, ks1 = 42u;
  constexpr uint32_t ks2 = 0x1BD11BDAu ^ ks0 ^ ks1;
  x0 += ks0; x1 += ks1;
#define TFR(r) { x0 += x1; x1 = rotl32(x1, (r)); x1 ^= x0; }
  TFR(13) TFR(15) TFR(26) TFR(6)
  x0 += ks1; x1 += ks2 + 1u;
  TFR(17) TFR(29) TFR(16) TFR(24)
  x0 += ks2; x1 += ks0 + 2u;
  TFR(13) TFR(15) TFR(26) TFR(6)
  x0 += ks0; x1 += ks1 + 3u;
  TFR(17) TFR(29) TFR(16) TFR(24)
  x0 += ks1; x1 += ks2 + 4u;
  TFR(13) TFR(15) TFR(26) TFR(6)
  x0 += ks2; x1 += ks0 + 5u;
#undef TFR
  o0 = x0; o1 = x1;
}

// composite key: (bits23+1) << 14 | (16383-col). Larger = better; equal bits
// -> smaller col wins (matches jax.lax.top_k tie-break). Unique per row.
// 0 is the "empty" sentinel (real comps are >= 1<<14).
__device__ __forceinline__ uint64_t mkcomp(uint32_t bits, int c) {
  return (((uint64_t)(bits >> 9) + 1ull) << 14) | (uint64_t)(16383 - c);
}

// branchless top-2 insert (a >= b invariant)
__device__ __forceinline__ void ins2(uint64_t v, uint64_t& a, uint64_t& b) {
  const uint64_t lo = v < a ? v : a;
  a = v > a ? v : a;
  b = lo > b ? lo : b;
}

// Wave-synchronous top-20 selection for one row: one full wave, zero block
// barriers. Lane owns threads tb..tb+3; each thread contributes a depth-2
// register-cached candidate list (top-2 above TH). When a thread's cache is
// exhausted, ALL 64 lanes cooperatively rescan its 64 columns (1 hash per
// lane + 6-step shfl max, NO threshold) for its next candidate strictly
// below the last consumed value.
__device__ __forceinline__ void wave_select(
    const uint64_t (*cand)[2], int* selX, int rbase, int hi, int4 p) {
  const int lane = threadIdx.x & 63;
  const int tb = lane << 2;
  const uint64_t laneu = (uint64_t)lane;
  uint64_t cur0 = cand[tb + 0][0], nxt0 = cand[tb + 0][1];
  uint64_t cur1 = cand[tb + 1][0], nxt1 = cand[tb + 1][1];
  uint64_t cur2 = cand[tb + 2][0], nxt2 = cand[tb + 2][1];
  uint64_t cur3 = cand[tb + 3][0], nxt3 = cand[tb + 3][1];
  for (int it = 0; it < NNEG; ++it) {
    uint64_t m = (cur0 << 8) | laneu;
    uint64_t t = (cur1 << 8) | 0x40ull | laneu; if (t > m) m = t;
    t = (cur2 << 8) | 0x80ull | laneu;          if (t > m) m = t;
    t = (cur3 << 8) | 0xC0ull | laneu;          if (t > m) m = t;
#pragma unroll
    for (int o = 32; o; o >>= 1) {
      const uint64_t y = (uint64_t)__shfl_xor((unsigned long long)m, o, 64);
      if (y > m) m = y;
    }
    if (lane == 0) selX[NPOS + it] = 16383 - (int)((m >> 8) & 0x3FFFull);
    const int owner = (int)(m & 63ull);
    const int slot  = (int)((m >> 6) & 3ull);
    const uint64_t bound = m >> 8;
    const uint64_t mynxt = slot == 0 ? nxt0 : slot == 1 ? nxt1
                         : slot == 2 ? nxt2 : nxt3;
    const uint64_t ownnxt =
        (uint64_t)__shfl((unsigned long long)mynxt, owner, 64);
    if (ownnxt) {                       // wave-uniform branch
      if (lane == owner) {
        if      (slot == 0) { cur0 = ownnxt; nxt0 = 0; }
        else if (slot == 1) { cur1 = ownnxt; nxt1 = 0; }
        else if (slot == 2) { cur2 = ownnxt; nxt2 = 0; }
        else                { cur3 = ownnxt; nxt3 = 0; }
      }
    } else {                            // cooperative rebuild (rare)
      const int thr = (owner << 2) | slot;
      const int col = (((lane >> 2) * THREADS + thr) << 2) + (lane & 3);
      uint32_t o0, o1;
      tf2x32((uint32_t)(rbase + col), (uint32_t)(rbase + col) + 0x2000000u, o0, o1);
      uint64_t v = mkcomp(hi ? o1 : o0, col);
      if (col == p.x || col == p.y || col == p.z || col == p.w || v >= bound)
        v = 0;
#pragma unroll
      for (int o = 32; o; o >>= 1) {
        const uint64_t y = (uint64_t)__shfl_xor((unsigned long long)v, o, 64);
        if (y > v) v = y;
      }
      if (lane == owner) {
        if      (slot == 0) cur0 = v;
        else if (slot == 1) cur1 = v;
        else if (slot == 2) cur2 = v;
        else                cur3 = v;
      }
    }
  }
}

// ---- single fused kernel: stream labels + hash + select + sim + BCE ----
__global__ __launch_bounds__(THREADS, 2) void supcon_fused(
    const float* __restrict__ feat, const float* __restrict__ proto,
    const int* __restrict__ lab, float* __restrict__ row_ws) {
  __shared__ uint64_t candL[THREADS][2];
  __shared__ uint64_t candH[THREADS][2];
  __shared__ int selL[NSEL], selH[NSEL];
  __shared__ int posCnt[2];
  __shared__ int posBuf[2][4];
  __shared__ float ffL[D], ffH[D];
  __shared__ float normL, normH;
  __shared__ float bces[2 * NSEL];

  const int tid = threadIdx.x;
  const int r = blockIdx.x;            // low row; pairs with r+HALF
  const int rbase = r * C;             // threefry x0 base (< 2^25)

  if (tid < 2) posCnt[tid] = 0;
  __syncthreads();

  // ---- Phase A: stream both label rows (prefetched), hash, thresholded
  //      per-thread top-2 per row (4 live u64). Hot path per column-pair:
  //      threefry + 2 cndmask + 2 cmp. Positive capture is a rare per-quad
  //      branch; exclusion is branchless (label forces hash to 0 < TH).
  const int4* labL4 = reinterpret_cast<const int4*>(lab + (size_t)rbase);
  const int4* labH4 = reinterpret_cast<const int4*>(lab + ((size_t)r + HALF) * C);
  uint64_t L0 = 0, L1 = 0, H0 = 0, H1 = 0;
  int4 lL = labL4[tid];
  int4 lH = labH4[tid];
  for (int j = 0; j < QPT; ++j) {
    int4 nL, nH;
    if (j + 1 < QPT) {                  // prefetch next quad pair
      nL = labL4[(j + 1) * THREADS + tid];
      nH = labH4[(j + 1) * THREADS + tid];
    }
    const int cq = (j * THREADS + tid) << 2;
    // rare positive capture (P ~ 1e-3 per lane per quad per row)
    if (lL.x | lL.y | lL.z | lL.w) {
      if (lL.x) { int s = atomicAdd(&posCnt[0], 1); if (s < 4) posBuf[0][s] = cq; }
      if (lL.y) { int s = atomicAdd(&posCnt[0], 1); if (s < 4) posBuf[0][s] = cq + 1; }
      if (lL.z) { int s = atomicAdd(&posCnt[0], 1); if (s < 4) posBuf[0][s] = cq + 2; }
      if (lL.w) { int s = atomicAdd(&posCnt[0], 1); if (s < 4) posBuf[0][s] = cq + 3; }
    }
    if (lH.x | lH.y | lH.z | lH.w) {
      if (lH.x) { int s = atomicAdd(&posCnt[1], 1); if (s < 4) posBuf[1][s] = cq; }
      if (lH.y) { int s = atomicAdd(&posCnt[1], 1); if (s < 4) posBuf[1][s] = cq + 1; }
      if (lH.z) { int s = atomicAdd(&posCnt[1], 1); if (s < 4) posBuf[1][s] = cq + 2; }
      if (lH.w) { int s = atomicAdd(&posCnt[1], 1); if (s < 4) posBuf[1][s] = cq + 3; }
    }
    uint32_t o0, o1;
#define DOCOL(i, LX, HX) {                                                     \
    const int c = cq + (i);                                                    \
    tf2x32((uint32_t)(rbase + c), (uint32_t)(rbase + c) + 0x2000000u, o0, o1); \
    const uint32_t e0 = (LX) ? 0u : o0;                                        \
    const uint32_t e1 = (HX) ? 0u : o1;                                        \
    if (e0 >= TH) ins2(mkcomp(e0, c), L0, L1);                                 \
    if (e1 >= TH) ins2(mkcomp(e1, c), H0, H1); }
    DOCOL(0, lL.x, lH.x)
    DOCOL(1, lL.y, lH.y)
    DOCOL(2, lL.z, lH.z)
    DOCOL(3, lL.w, lH.w)
#undef DOCOL
    lL = nL; lH = nH;
  }
  candL[tid][0] = L0; candL[tid][1] = L1;
  candH[tid][0] = H0; candH[tid][1] = H1;
  __syncthreads();

  if (tid < 2) {   // sort the 4 positive cols ascending (jax top_k tie order)
    int a = posBuf[tid][0], b = posBuf[tid][1], c2 = posBuf[tid][2], d = posBuf[tid][3];
#define CSW(x, y) if (x > y) { int t_ = x; x = y; y = t_; }
    CSW(a, b) CSW(c2, d) CSW(a, c2) CSW(b, d) CSW(b, c2)
#undef CSW
    int* s = tid ? selH : selL;
    s[0] = a; s[1] = b; s[2] = c2; s[3] = d;
  }
  __syncthreads();

  // ---- Phase B: wave 0 selects L negs, wave 1 selects H negs,
  //      waves 2/3 load + normalize the two feature rows. No barriers inside.
  const int wv = tid >> 6;
  if (wv == 0) {
    const int4 p = { selL[0], selL[1], selL[2], selL[3] };
    wave_select(candL, selL, rbase, 0, p);
  } else if (wv == 1) {
    const int4 p = { selH[0], selH[1], selH[2], selH[3] };
    wave_select(candH, selH, rbase, 1, p);
  } else if (wv == 2) {
    const int l = tid & 63;
    const float a = feat[(size_t)r * D + l];
    const float b = feat[(size_t)r * D + 64 + l];
    ffL[l] = a; ffL[64 + l] = b;
    float s = a * a + b * b;
#pragma unroll
    for (int o = 32; o; o >>= 1) s += __shfl_xor(s, o, 64);
    if (l == 0) normL = s;
  } else {
    const int l = tid & 63;
    const float a = feat[((size_t)r + HALF) * D + l];
    const float b = feat[((size_t)r + HALF) * D + 64 + l];
    ffH[l] = a; ffH[64 + l] = b;
    float s = a * a + b * b;
#pragma unroll
    for (int o = 32; o; o >>= 1) s += __shfl_xor(s, o, 64);
    if (l == 0) normH = s;
  }
  __syncthreads();

  // ---- Phase C: 48 selected columns x 4 lanes each -> sim + BCE ----
  if (tid < 4 * 2 * NSEL) {
    const int ci = tid >> 2;            // 0..47
    const int k  = tid & 3;
    const bool isH = ci >= NSEL;
    const int g = isH ? ci - NSEL : ci;
    const int c = isH ? selH[g] : selL[g];
    const float* ff = isH ? ffH : ffL;
    const float4* pc = reinterpret_cast<const float4*>(proto + (size_t)c * D);
    float fp = 0.f, pp = 0.f;
#pragma unroll
    for (int qq = 0; qq < 8; ++qq) {
      const float4 pv = pc[k * 8 + qq];
      const int d0 = k * 32 + qq * 4;
      fp += ff[d0] * pv.x + ff[d0 + 1] * pv.y + ff[d0 + 2] * pv.z + ff[d0 + 3] * pv.w;
      pp += pv.x * pv.x + pv.y * pv.y + pv.z * pv.z + pv.w * pv.w;
    }
    fp += __shfl_xor(fp, 1, 64); pp += __shfl_xor(pp, 1, 64);
    fp += __shfl_xor(fp, 2, 64); pp += __shfl_xor(pp, 2, 64);
    if (k == 0) {
      const float x = (isH ? normH : normL) * pp;
      float rn = rsqrtf(x);
      rn = rn * (1.5f - 0.5f * x * rn * rn);   // 1 NR step for accuracy
      const float l = fp * rn * 10.0f;          // /TEMP, TEMP=0.1
      const float tgt = (g < NPOS) ? 0.25f : 0.0f;
      bces[ci] = fmaxf(l, 0.f) - l * tgt + __logf(1.0f + __expf(-fabsf(l)));
    }
  }
  __syncthreads();
  if (tid < 2) {
    float s = 0.f;
    const int base = tid * NSEL;
#pragma unroll
    for (int i = 0; i < NSEL; ++i) s += bces[base + i];
    row_ws[tid ? (r + HALF) : r] = s * (1.0f / NSEL);
  }
}

__global__ __launch_bounds__(THREADS) void supcon_reduce(
    const float* __restrict__ ws, float* __restrict__ out) {
  __shared__ float red[THREADS];
  const int tid = threadIdx.x;
  float s = 0.f;
#pragma unroll
  for (int j = 0; j < BS / THREADS; ++j) s += ws[j * THREADS + tid];
  red[tid] = s;
  __syncthreads();
  for (int o = THREADS / 2; o > 0; o >>= 1) {
    if (tid < o) red[tid] += red[tid + o];
    __syncthreads();
  }
  if (tid == 0) out[0] = red[0] * (1.0f / BS);
}

extern "C" void kernel_launch(void* const* d_in, const int* in_sizes, int n_in,
                              void* d_out, int out_size, void* d_ws, size_t ws_size,
                              hipStream_t stream) {
  (void)in_sizes; (void)n_in; (void)out_size; (void)ws_size;
  const float* feat  = (const float*)d_in[0];
  const float* proto = (const float*)d_in[1];
  const int*   lab   = (const int*)d_in[2];
  float* out = (float*)d_out;
  float* ws  = (float*)d_ws;   // [0..4095]: per-row mean-BCE

  supcon_fused<<<dim3(HALF), dim3(THREADS), 0, stream>>>(feat, proto, lab, ws);
  supcon_reduce<<<dim3(1), dim3(THREADS), 0, stream>>>(ws, out);
}